// Round 20
// baseline (252.700 us; speedup 1.0000x reference)
//
#include <hip/hip_runtime.h>
#include <stdint.h>
#include <math.h>

// Sizes
#define NN 512   // N_NODES
#define HID 64
#define LAT 256
#define TS 10
#define BAT 64

#define DEVFN static __device__ __forceinline__

DEVFN uint32_t rotl32(uint32_t v, int d) { return (v << d) | (v >> (32 - d)); }

// Threefry-2x32, 20 rounds (JAX threefry2x32_p). key=(k0,k1), count=(x0,x1).
DEVFN void threefry2x32(uint32_t k0, uint32_t k1, uint32_t x0, uint32_t x1,
                        uint32_t& o0, uint32_t& o1) {
  uint32_t ks0 = k0, ks1 = k1, ks2 = k0 ^ k1 ^ 0x1BD11BDAu;
  x0 += ks0; x1 += ks1;
  x0 += x1; x1 = rotl32(x1, 13); x1 ^= x0;
  x0 += x1; x1 = rotl32(x1, 15); x1 ^= x0;
  x0 += x1; x1 = rotl32(x1, 26); x1 ^= x0;
  x0 += x1; x1 = rotl32(x1, 6);  x1 ^= x0;
  x0 += ks1; x1 += ks2 + 1u;
  x0 += x1; x1 = rotl32(x1, 17); x1 ^= x0;
  x0 += x1; x1 = rotl32(x1, 29); x1 ^= x0;
  x0 += x1; x1 = rotl32(x1, 16); x1 ^= x0;
  x0 += x1; x1 = rotl32(x1, 24); x1 ^= x0;
  x0 += ks2; x1 += ks0 + 2u;
  x0 += x1; x1 = rotl32(x1, 13); x1 ^= x0;
  x0 += x1; x1 = rotl32(x1, 15); x1 ^= x0;
  x0 += x1; x1 = rotl32(x1, 26); x1 ^= x0;
  x0 += x1; x1 = rotl32(x1, 6);  x1 ^= x0;
  x0 += ks0; x1 += ks1 + 3u;
  x0 += x1; x1 = rotl32(x1, 17); x1 ^= x0;
  x0 += x1; x1 = rotl32(x1, 29); x1 ^= x0;
  x0 += x1; x1 = rotl32(x1, 16); x1 ^= x0;
  x0 += x1; x1 = rotl32(x1, 24); x1 ^= x0;
  x0 += ks1; x1 += ks2 + 4u;
  x0 += x1; x1 = rotl32(x1, 13); x1 ^= x0;
  x0 += x1; x1 = rotl32(x1, 15); x1 ^= x0;
  x0 += x1; x1 = rotl32(x1, 26); x1 ^= x0;
  x0 += x1; x1 = rotl32(x1, 6);  x1 ^= x0;
  x0 += ks2; x1 += ks0 + 5u;
  o0 = x0; o1 = x1;
}

DEVFN float sigmoidf_(float x) { return 1.0f / (1.0f + expf(-x)); }

// JAX gumbel from 32 random bits: uniform in [tiny, 1), g = -log(-log(u))
DEVFN float gumbel_bits(uint32_t bits) {
  const float tiny = 1.17549435e-38f;
  float f = __uint_as_float((bits >> 9) | 0x3F800000u) - 1.0f;
  float u = f * (1.0f - tiny) + tiny;
  u = fmaxf(tiny, u);
  return -logf(-logf(u));
}

// 256-thread block reduction (4 waves of 64)
DEVFN float block_red256(float v, float* red, bool ismax) {
  #pragma unroll
  for (int o = 32; o > 0; o >>= 1) {
    float w = __shfl_down(v, o, 64);
    v = ismax ? fmaxf(v, w) : v + w;
  }
  if ((threadIdx.x & 63) == 0) red[threadIdx.x >> 6] = v;
  __syncthreads();
  float r = ismax ? fmaxf(fmaxf(red[0], red[1]), fmaxf(red[2], red[3]))
                  : ((red[0] + red[1]) + (red[2] + red[3]));
  __syncthreads();
  return r;
}

// 64-lane wave butterfly sum
DEVFN float wave_red_sum64(float v) {
  #pragma unroll
  for (int o = 32; o > 0; o >>= 1) v += __shfl_xor(v, o, 64);
  return v;
}

// float4 dot-step, k-ascending order preserved
#define ACC4(acc, x4, w4) { acc += (x4).x * (w4).x; acc += (x4).y * (w4).y; \
                            acc += (x4).z * (w4).z; acc += (x4).w * (w4).w; }

// ================ prep: whht || wp1 || gitab || flow (all independent) =========
__global__ __launch_bounds__(384) void prep_kernel(
    const float* __restrict__ w_hh, float* __restrict__ w_hhT,
    const float* __restrict__ X, const float* __restrict__ wp1,
    const float* __restrict__ bp1, float* __restrict__ x0,
    const float* __restrict__ w_ih, const float* __restrict__ b_ih,
    float* __restrict__ gi_table,
    const float* __restrict__ Z, const float* __restrict__ fs_w,
    const float* __restrict__ fs_b, const float* __restrict__ ft_w,
    const float* __restrict__ ft_b, float* __restrict__ z2p) {
  const int tid = threadIdx.x;
  if (blockIdx.x < 128) {
    const int idx = blockIdx.x * 384 + tid;   // 128*384 = 49152
    const int k4 = idx / 1536, rem = idx % 1536;
    const int t = rem >> 2, kl = rem & 3;
    w_hhT[idx] = w_hh[(k4 * 4 + kl) * 384 + t];
  } else if (blockIdx.x < 288) {
    const int r0 = (blockIdx.x - 128) * 4;
    const int g = tid >> 6, c = tid & 63;
    __shared__ float Xb[4][NN];      // 8KB
    __shared__ float Wb[128 * 64];   // 32KB
    for (int i = tid; i < 4 * NN; i += 384)
      Xb[i >> 9][i & 511] = X[r0 * NN + i];
    float acc = (tid < 256) ? bp1[c] : 0.0f;
    for (int ch = 0; ch < 4; ch++) {
      const int n0 = ch * 128;
      __syncthreads();
      for (int i = tid; i < 128 * 64; i += 384) {
        int k = i >> 6, cc = i & 63;
        Wb[((k >> 2) * 64 + cc) * 4 + (k & 3)] = wp1[(n0 + k) * 64 + cc];
      }
      __syncthreads();
      if (tid < 256) {
        #pragma unroll 8
        for (int n4 = 0; n4 < 32; n4++) {
          float4 w4 = *(const float4*)&Wb[(n4 * 64 + c) * 4];
          float4 x4 = *(const float4*)&Xb[g][n0 + n4 * 4];
          ACC4(acc, x4, w4);
        }
      }
    }
    if (tid < 256) x0[(r0 + g) * HID + c] = acc;
  } else if (blockIdx.x < 388) {
    const int v = blockIdx.x - 288;  // 0..99
    const int t = tid;               // col 0..383
    __shared__ float temb[256];
    if (t < 256) {
      float fr = (float)exp((double)(t & 127) * (10.0 / 127.0));  // np f64->f32
      float arg = (float)v * fr;
      temb[t] = (t < 128) ? sinf(arg) : cosf(arg);
    }
    __syncthreads();
    float acc = b_ih[t];
    for (int k = 0; k < 256; k++) acc += temb[k] * w_ih[k * 384 + t];
    gi_table[v * 384 + t] = acc;
  } else {
    const int n = (blockIdx.x - 388) * 3 + (tid >> 7);
    const int c = tid & 127;
    __shared__ float z1s[3][128];
    if (n < NN) z1s[tid >> 7][c] = Z[n * LAT + c];
    __syncthreads();
    if (n < NN) {
      const float* z1 = z1s[tid >> 7];
      float a = fs_b[c], t = ft_b[c];
      for (int k = 0; k < 128; k++) {
        float zz = z1[k];
        a += zz * fs_w[k * 128 + c];
        t += zz * ft_w[k * 128 + c];
      }
      z2p[n * 128 + c] = sigmoidf_(a) * Z[n * LAT + 128 + c] + t;
    }
  }
}

// ================ fused enc (blocks 0..63) + gru 4-node (blocks 64..191) =======
__global__ __launch_bounds__(768) void encgru_kernel(
    const float* __restrict__ x0,
    const float* __restrict__ in_w, const float* __restrict__ in_b,
    const float* __restrict__ out_w, const float* __restrict__ out_b,
    const float* __restrict__ l1_w, const float* __restrict__ l1_b,
    const float* __restrict__ l2_w, const float* __restrict__ l2_b,
    const float* __restrict__ g1, const float* __restrict__ b1,
    const float* __restrict__ g2, const float* __restrict__ b2,
    float* __restrict__ x_enc,
    const int* __restrict__ tctx, const float* __restrict__ w_hhT4,
    const float* __restrict__ b_hh, const float* __restrict__ gi_table,
    const float* __restrict__ tp_w, const float* __restrict__ tp_b,
    const float* __restrict__ z2p, float* __restrict__ z2f) {
  __shared__ float smem[28176];   // 112.7KB union
  const int tid = threadIdx.x;

  if (blockIdx.x < 64) {
    const int b = blockIdx.x;
    const int s = tid >> 6, c = tid & 63;
    float* WbA  = smem;            // 12288
    float* WbB  = smem + 12288;    // 12288
    float* xx   = smem + 24576;    // 640
    float* qkv  = smem + 25216;    // 1920
    float* scb  = smem + 27136;    // 400
    float* tmpv = smem + 27536;    // 640

    if (tid < 640) xx[s * 64 + c] = x0[b * 640 + tid];

    for (int l = 0; l < 2; l++) {
      const float* inw = in_w + l * HID * 192; const float* inb = in_b + l * 192;
      const float* ow  = out_w + l * HID * HID; const float* ob = out_b + l * HID;
      const float* w1  = l1_w + l * HID * HID; const float* bb1 = l1_b + l * HID;
      const float* w2  = l2_w + l * HID * HID; const float* bb2 = l2_b + l * HID;
      const float* gg1 = g1 + l * HID; const float* be1 = b1 + l * HID;
      const float* gg2 = g2 + l * HID; const float* be2 = b2 + l * HID;

      __syncthreads();
      for (int i = tid; i < 12288; i += 768) {
        int k = i / 192, cc = i % 192;
        WbA[((k >> 2) * 192 + cc) * 4 + (k & 3)] = inw[i];
      }
      for (int i = tid; i < 12288; i += 768) {
        int m = i >> 12, rem = i & 4095, k = rem >> 6, cc = rem & 63;
        float v = (m == 0) ? ow[rem] : (m == 1) ? w1[rem] : w2[rem];
        WbB[m * 4096 + ((k >> 2) * 64 + cc) * 4 + (k & 3)] = v;
      }
      __syncthreads();

      if (tid < 640) {
        #pragma unroll
        for (int part = 0; part < 3; part++) {
          const int cc = part * 64 + c;
          float acc = inb[cc];
          #pragma unroll
          for (int k4 = 0; k4 < 16; k4++) {
            float4 w4 = *(const float4*)&WbA[(k4 * 192 + cc) * 4];
            float4 x4 = *(const float4*)&xx[s * 64 + k4 * 4];
            ACC4(acc, x4, w4);
          }
          qkv[s * 192 + cc] = acc;
        }
      }
      __syncthreads();

      if (tid < 40) {
        const int h = tid / 10, r = tid % 10;
        float e[10];
        for (int t = 0; t < 10; t++) {
          float acc = 0.0f;
          for (int d = 0; d < 16; d++)
            acc += qkv[r * 192 + h * 16 + d] * qkv[t * 192 + 64 + h * 16 + d];
          e[t] = acc * 0.25f;
        }
        float m = -1e30f;
        for (int t = 0; t < 10; t++) m = fmaxf(m, e[t]);
        float sum = 0.0f;
        for (int t = 0; t < 10; t++) { e[t] = expf(e[t] - m); sum += e[t]; }
        float inv = 1.0f / sum;
        for (int t = 0; t < 10; t++) scb[h * 100 + r * 10 + t] = e[t] * inv;
      }
      __syncthreads();

      float v1 = 0.0f;
      if (tid < 640) {
        const int h = c >> 4;
        float acc = 0.0f;
        for (int t = 0; t < 10; t++)
          acc += scb[h * 100 + s * 10 + t] * qkv[t * 192 + 128 + c];
        tmpv[s * 64 + c] = acc;
      }
      __threadfence_block();
      if (tid < 640) {
        float acc = ob[c] + xx[s * 64 + c];
        #pragma unroll
        for (int k4 = 0; k4 < 16; k4++) {
          float4 w4 = *(const float4*)&WbB[(k4 * 64 + c) * 4];
          float4 x4 = *(const float4*)&tmpv[s * 64 + k4 * 4];
          ACC4(acc, x4, w4);
        }
        float mu = wave_red_sum64(acc) * (1.0f / 64.0f);
        float d = acc - mu;
        float var = wave_red_sum64(d * d) * (1.0f / 64.0f);
        float rs = rsqrtf(var + 1e-5f);
        v1 = d * rs * gg1[c] + be1[c];
        xx[s * 64 + c] = v1;
      }
      __threadfence_block();
      if (tid < 640) {
        float acc = bb1[c];
        #pragma unroll
        for (int k4 = 0; k4 < 16; k4++) {
          float4 w4 = *(const float4*)&WbB[4096 + (k4 * 64 + c) * 4];
          float4 x4 = *(const float4*)&xx[s * 64 + k4 * 4];
          ACC4(acc, x4, w4);
        }
        tmpv[s * 64 + c] = fmaxf(acc, 0.0f);
      }
      __threadfence_block();
      if (tid < 640) {
        float acc = bb2[c] + v1;
        #pragma unroll
        for (int k4 = 0; k4 < 16; k4++) {
          float4 w4 = *(const float4*)&WbB[8192 + (k4 * 64 + c) * 4];
          float4 x4 = *(const float4*)&tmpv[s * 64 + k4 * 4];
          ACC4(acc, x4, w4);
        }
        float mu = wave_red_sum64(acc) * (1.0f / 64.0f);
        float d = acc - mu;
        float var = wave_red_sum64(d * d) * (1.0f / 64.0f);
        float rs = rsqrtf(var + 1e-5f);
        xx[s * 64 + c] = d * rs * gg2[c] + be2[c];
      }
      __threadfence_block();
    }
    if (tid < 640) x_enc[b * 640 + tid] = xx[s * 64 + c];
  } else {
    const int n0 = (blockIdx.x - 64) * 4;
    const int half = tid >= 384 ? 1 : 0;
    const int c = tid - half * 384;
    float* h      = smem;             // 512
    float* part   = smem + 512;       // 3072
    float* gi_lds = smem + 3584;      // 15360
    float* tpw    = smem + 18944;     // 10
    for (int i = tid; i < 4 * TS * 384; i += 768) {
      int g = i / 3840, rem = i % 3840, s = rem / 384, col = rem % 384;
      gi_lds[(g * TS + s) * 384 + col] = gi_table[tctx[(n0 + g) * 10 + s] * 384 + col];
    }
    if (tid < TS) tpw[tid] = tp_w[tid];
    const float4* wbase = (const float4*)w_hhT4 + (half * 16) * 384 + c;
    const float bhh = (half == 0) ? b_hh[c] : 0.0f;
    float acc_tp = 0.0f;
    if (tid < 512) h[tid] = 0.0f;
    __syncthreads();
    #pragma unroll
    for (int s = 0; s < 10; s++) {
      float accs[4];
      #pragma unroll
      for (int g = 0; g < 4; g++) accs[g] = bhh;
      #pragma unroll
      for (int k4 = 0; k4 < 16; k4++) {
        float4 w4 = wbase[k4 * 384];
        #pragma unroll
        for (int g = 0; g < 4; g++) {
          float4 hv = *(const float4*)&h[g * 128 + (half * 16 + k4) * 4];
          ACC4(accs[g], hv, w4);
        }
      }
      #pragma unroll
      for (int g = 0; g < 4; g++) part[(half * 4 + g) * 384 + c] = accs[g];
      __syncthreads();
      if (tid < 512) {
        const int g = tid >> 7, cc = tid & 127;
        const float* gi = gi_lds + (g * TS + s) * 384;
        float gh_r = part[g * 384 + cc]           + part[(4 + g) * 384 + cc];
        float gh_z = part[g * 384 + 128 + cc]     + part[(4 + g) * 384 + 128 + cc];
        float gh_n = part[g * 384 + 256 + cc]     + part[(4 + g) * 384 + 256 + cc];
        float r = sigmoidf_(gi[cc] + gh_r);
        float z = sigmoidf_(gi[128 + cc] + gh_z);
        float nn2 = tanhf(gi[256 + cc] + r * gh_n);
        float hn = (1.0f - z) * nn2 + z * h[g * 128 + cc];
        h[g * 128 + cc] = hn;
        acc_tp += hn * tpw[s];
      }
      __syncthreads();
    }
    if (tid < 512) {
      const int g = tid >> 7, cc = tid & 127;
      z2f[(n0 + g) * 128 + cc] = z2p[(n0 + g) * 128 + cc] + acc_tp + tp_b[0];
    }
  }
}

// ================ fused wp2 (blocks 0..127) + znA (blocks 128..639) ============
__global__ __launch_bounds__(256) void wp2zna_kernel(
    const float* __restrict__ x_enc, const float* __restrict__ wp2,
    const float* __restrict__ bp2,
    float* __restrict__ x_inst, float* __restrict__ x_lag,
    const float* __restrict__ Z, const float* __restrict__ z2f,
    const float* __restrict__ ltn_w, const float* __restrict__ ltn_b,
    float* __restrict__ zn_ws) {
  const int tid = threadIdx.x;
  if (blockIdx.x < 128) {
    const int b = blockIdx.x >> 1, half = blockIdx.x & 1;
    const int n = half * 256 + tid;
    __shared__ float xxl[640];
    __shared__ float Wb[32 * 256];   // 32KB
    for (int i = tid; i < 640; i += 256) xxl[i] = x_enc[b * 640 + i];
    float accs[10];
    #pragma unroll
    for (int si = 0; si < 10; si++) accs[si] = 0.0f;
    for (int ch = 0; ch < 2; ch++) {
      __syncthreads();
      for (int i = tid; i < 32 * 256; i += 256)
        Wb[i] = wp2[(ch * 32 + (i >> 8)) * NN + half * 256 + (i & 255)];
      __syncthreads();
      for (int k = 0; k < 32; k++) {
        float w = Wb[k * 256 + tid];
        #pragma unroll
        for (int si = 0; si < 10; si++) accs[si] += xxl[si * 64 + ch * 32 + k] * w;
      }
    }
    float bias = bp2[n];
    x_inst[b * NN + n] = accs[0] + bias;
    float lag = 0.0f;
    for (int si = 1; si < 10; si++) lag += accs[si];
    x_lag[b * NN + n] = lag * (1.0f / 9.0f) + bias;
  } else {
    const int bid = blockIdx.x - 128;
    const int nt = bid >> 2, cg = bid & 3;
    const int oo = tid & 127, gsel = tid >> 7;
    const int o = cg * 128 + oo;
    const int n0 = nt * 4;
    __shared__ float zcat[4][LAT];   // 4KB
    for (int i = tid; i < 4 * LAT; i += 256) {
      int g = i >> 8, k = i & 255;
      zcat[g][k] = (k < 128) ? Z[(n0 + g) * LAT + k] : z2f[(n0 + g) * 128 + (k - 128)];
    }
    __syncthreads();
    const float bias = ltn_b[o];
    float accA = bias, accB = bias;
    const int g0 = gsel, g1 = gsel + 2;
    for (int k = 0; k < LAT; k++) {
      float w = ltn_w[k * NN + o];
      accA += zcat[g0][k] * w;
      accB += zcat[g1][k] * w;
    }
    zn_ws[(n0 + g0) * NN + o] = accA;
    zn_ws[(n0 + g1) * NN + o] = accB;
  }
}

// ================ fused adj (blocks 0..1023) + znB (blocks 1024..1535) =========
__global__ __launch_bounds__(256) void adjznb_kernel(
    const float* __restrict__ x_inst, const float* __restrict__ x_lag,
    const float* __restrict__ es_now, const float* __restrict__ es_lag,
    const float* __restrict__ prior, float* __restrict__ out,
    const float* __restrict__ zn_ws,
    const float* __restrict__ wl, const float* __restrict__ bl,
    const float* __restrict__ wr, const float* __restrict__ br,
    float* __restrict__ xl, float* __restrict__ xr) {
  const int tid = threadIdx.x;
  if (blockIdx.x < 1024) {
    const int k = blockIdx.x & 511;
    const int v = blockIdx.x >> 9;
    const float* xs = v ? x_lag : x_inst;
    const float* es = v ? es_lag : es_now;
    __shared__ float ck[BAT];
    __shared__ float red[4];
    if (tid < BAT) ck[tid] = xs[tid * NN + k];
    __syncthreads();
    uint32_t ka, kb, t0, t1;
    threefry2x32(0u, 42u, 0u, (uint32_t)v, ka, kb);
    float vals[2];
    #pragma unroll
    for (int jj = 0; jj < 2; jj++) {
      int j = tid + jj * 256;
      float acc = 0.0f;
      for (int bb = 0; bb < BAT; bb++) acc += ck[bb] * xs[bb * NN + j];
      if (v) acc = sigmoidf_(acc);
      threefry2x32(ka, kb, 0u, (uint32_t)(k * NN + j), t0, t1);
      vals[jj] = acc + gumbel_bits(t0 ^ t1);
    }
    float m = block_red256(fmaxf(vals[0], vals[1]), red, true);
    float e0 = expf(vals[0] - m), e1 = expf(vals[1] - m);
    float s = block_red256(e0 + e1, red, false);
    float inv = 1.0f / s;
    #pragma unroll
    for (int jj = 0; jj < 2; jj++) {
      int j = tid + jj * 256;
      float a = (jj ? e1 : e0) * inv;
      float t = es[k * NN + j] + prior[k * NN + j] + a;
      float sg = sigmoidf_(t);
      sg = fminf(fmaxf(sg, 0.0f), 1.0f);
      if (j == k) sg = 0.0f;
      if (sg == 0.0f) sg = 1e-8f;
      out[v * NN * NN + k * NN + j] = sg;
    }
  } else {
    const int bid = blockIdx.x - 1024;
    const int nt = bid >> 2, cg = bid & 3;
    const int o = cg * 64 + (tid & 63), g = tid >> 6;
    const int n = nt * 4 + g;
    __shared__ float znr[4][NN];   // 8KB
    for (int i = tid; i < 4 * NN; i += 256)
      znr[i >> 9][i & 511] = zn_ws[(nt * 4 + (i >> 9)) * NN + (i & 511)];
    __syncthreads();
    float accL = bl[o], accR = br[o];
    for (int k = 0; k < NN; k++) {
      float z = znr[g][k];
      accL += z * wl[k * 256 + o];
      accR += z * wr[k * 256 + o];
    }
    xl[n * 256 + o] = accL;
    xr[n * 256 + o] = accR;
  }
}

// ================ gatmega: e + softmax + xemb + gl-GEMM, 4 rows/block ==========
// grid 128 x 256 threads. e kept entirely in LDS (no e_ws round-trip).
// e: c-ascending single chain (bitwise == gatE4); softmax: block_red256
// (bitwise == gatS); xemb: j ascending; gl: bias + k ascending (== glgemm).
__global__ __launch_bounds__(256) void gatmega_kernel(
    const float* __restrict__ xl, const float* __restrict__ xr,
    const float* __restrict__ attw, const float* __restrict__ gbias,
    const float* __restrict__ gl_w, const float* __restrict__ gl_b,
    float* __restrict__ out_mean, float* __restrict__ out_scale) {
  const int i0 = blockIdx.x * 4;
  const int tid = threadIdx.x;
  __shared__ float xls[64][257];    // 64 staged xl rows, pad-257 (conflict-free)
  __shared__ float e[4][4][512];    // [r][h][j] 32KB
  __shared__ float xr4[4][256];
  __shared__ float aw[256];
  __shared__ float xemb_l[4][256];
  __shared__ float red[4];
  for (int i = tid; i < 1024; i += 256)
    xr4[i >> 8][i & 255] = xr[(i0 + (i >> 8)) * 256 + (i & 255)];
  aw[tid] = attw[tid];
  // ---- phase 1: e[r][h][j] over 8 tiles of 64 j ----
  for (int t = 0; t < 8; t++) {
    __syncthreads();   // prior tile's reads done / xr4+aw ready (t==0)
    for (int idx = tid; idx < 64 * 64; idx += 256) {
      int j = idx >> 6, c4 = idx & 63;
      float4 v = *(const float4*)&xl[(t * 64 + j) * 256 + c4 * 4];
      xls[j][c4 * 4 + 0] = v.x;
      xls[j][c4 * 4 + 1] = v.y;
      xls[j][c4 * 4 + 2] = v.z;
      xls[j][c4 * 4 + 3] = v.w;
    }
    __syncthreads();
    #pragma unroll
    for (int q = 0; q < 4; q++) {
      const int idx = tid + q * 256;          // 0..1023
      const int r = idx >> 8;
      const int h = (idx >> 6) & 3;
      const int j = idx & 63;
      float acc = 0.0f;
      const int cb = h * 64;
      for (int c = 0; c < 64; c++) {
        float v = xr4[r][cb + c] + xls[j][cb + c];
        v = (v >= 0.0f) ? v : 0.2f * v;
        acc += v * aw[cb + c];
      }
      e[r][h][t * 64 + j] = acc;
    }
  }
  __syncthreads();
  // ---- phase 2: softmax per (r,h), exact gatS reduction order ----
  for (int r = 0; r < 4; r++) {
    for (int h = 0; h < 4; h++) {
      float v0 = e[r][h][tid], v1 = e[r][h][tid + 256];
      float m = block_red256(fmaxf(v0, v1), red, true);
      float e0 = expf(v0 - m), e1 = expf(v1 - m);
      float ssum = block_red256(e0 + e1, red, false);
      float inv = 1.0f / ssum;
      e[r][h][tid] = e0 * inv;
      e[r][h][tid + 256] = e1 * inv;
    }
  }
  __syncthreads();
  // ---- phase 3: xemb[r][o] = sum_j alpha[r][h(o)][j] * xl[j][o] + gbias ----
  {
    const int h = tid >> 6;
    float a0 = 0.0f, a1 = 0.0f, a2 = 0.0f, a3 = 0.0f;
    #pragma unroll 4
    for (int j = 0; j < 512; j++) {
      float x = xl[j * 256 + tid];   // lanes consecutive -> coalesced
      a0 += e[0][h][j] * x;
      a1 += e[1][h][j] * x;
      a2 += e[2][h][j] * x;
      a3 += e[3][h][j] * x;
    }
    float gb = gbias[tid];
    xemb_l[0][tid] = a0 + gb;
    xemb_l[1][tid] = a1 + gb;
    xemb_l[2][tid] = a2 + gb;
    xemb_l[3][tid] = a3 + gb;
  }
  __syncthreads();
  // ---- phase 4: ml = xemb @ gl_w + gl_b; mean/scale epilogue ----
  #pragma unroll
  for (int q = 0; q < 4; q++) {
    const int col = tid + q * 256;
    const float bias = gl_b[col];
    float a0 = bias, a1 = bias, a2 = bias, a3 = bias;
    for (int k = 0; k < 256; k++) {
      float w = gl_w[k * 1024 + col];
      a0 += xemb_l[0][k] * w;
      a1 += xemb_l[1][k] * w;
      a2 += xemb_l[2][k] * w;
      a3 += xemb_l[3][k] * w;
    }
    float accs[4] = {a0, a1, a2, a3};
    if (col < 512) {
      #pragma unroll
      for (int r = 0; r < 4; r++) out_mean[(i0 + r) * NN + col] = accs[r];
    } else {
      #pragma unroll
      for (int r = 0; r < 4; r++) {
        float lv = fminf(fmaxf(accs[r], -5.0f), 2.0f);
        out_scale[(i0 + r) * NN + (col - 512)] = expf(0.5f * lv);
      }
    }
  }
}

extern "C" void kernel_launch(void* const* d_in, const int* in_sizes, int n_in,
                              void* d_out, int out_size, void* d_ws, size_t ws_size,
                              hipStream_t stream) {
  (void)in_sizes; (void)n_in; (void)out_size; (void)ws_size;
  const float* X        = (const float*)d_in[0];
  const float* Z        = (const float*)d_in[1];
  const float* es_now   = (const float*)d_in[2];
  const float* es_lag   = (const float*)d_in[3];
  const float* prior    = (const float*)d_in[4];
  const float* wp1      = (const float*)d_in[5];
  const float* bp1      = (const float*)d_in[6];
  const float* enc_in_w = (const float*)d_in[7];
  const float* enc_in_b = (const float*)d_in[8];
  const float* enc_out_w= (const float*)d_in[9];
  const float* enc_out_b= (const float*)d_in[10];
  const float* enc_l1_w = (const float*)d_in[11];
  const float* enc_l1_b = (const float*)d_in[12];
  const float* enc_l2_w = (const float*)d_in[13];
  const float* enc_l2_b = (const float*)d_in[14];
  const float* enc_g1   = (const float*)d_in[15];
  const float* enc_b1   = (const float*)d_in[16];
  const float* enc_g2   = (const float*)d_in[17];
  const float* enc_b2   = (const float*)d_in[18];
  const float* wp2      = (const float*)d_in[19];
  const float* bp2      = (const float*)d_in[20];
  const float* fs_w     = (const float*)d_in[21];
  const float* fs_b     = (const float*)d_in[22];
  const float* ft_w     = (const float*)d_in[23];
  const float* ft_b     = (const float*)d_in[24];
  const float* gru_w_ih = (const float*)d_in[25];
  const float* gru_w_hh = (const float*)d_in[26];
  const float* gru_b_ih = (const float*)d_in[27];
  const float* gru_b_hh = (const float*)d_in[28];
  const float* tp_w     = (const float*)d_in[29];
  const float* tp_b     = (const float*)d_in[30];
  const float* ltn_w    = (const float*)d_in[31];
  const float* ltn_b    = (const float*)d_in[32];
  const float* gat_wl   = (const float*)d_in[33];
  const float* gat_bl   = (const float*)d_in[34];
  const float* gat_wr   = (const float*)d_in[35];
  const float* gat_br   = (const float*)d_in[36];
  const float* gat_att  = (const float*)d_in[37];
  const float* gat_bias = (const float*)d_in[38];
  const float* gl_w     = (const float*)d_in[39];
  const float* gl_b     = (const float*)d_in[40];
  const int*   tctx     = (const int*)d_in[41];

  float* out = (float*)d_out;
  float* ws  = (float*)d_ws;
  // ws layout (floats)
  float* x_inst   = ws;                // 64*512
  float* x_lag    = ws + 32768;        // 64*512
  float* z2p      = ws + 65536;        // 512*128
  float* z2f      = ws + 131072;       // 512*128
  float* xl       = ws + 196608;       // 512*256
  float* xr       = ws + 327680;       // 512*256
  float* gi_table = ws + 458752;       // 100*384
  float* x0       = ws + 628224;       // 640*64
  float* x_enc    = ws + 669184;       // 640*64
  float* zn_ws    = ws + 710144;       // 512*512
  float* w_hhT4   = zn_ws;             // aliased; gru done before znA writes

  // fused pre-phase: whht || wp1 || gitab || flow
  prep_kernel<<<dim3(559), dim3(384), 0, stream>>>(
      gru_w_hh, w_hhT4, X, wp1, bp1, x0,
      gru_w_ih, gru_b_ih, gi_table,
      Z, fs_w, fs_b, ft_w, ft_b, z2p);
  // fused: enc (blocks 0..63) || gru (blocks 64..191)
  encgru_kernel<<<dim3(192), dim3(768), 0, stream>>>(
      x0, enc_in_w, enc_in_b, enc_out_w, enc_out_b,
      enc_l1_w, enc_l1_b, enc_l2_w, enc_l2_b,
      enc_g1, enc_b1, enc_g2, enc_b2, x_enc,
      tctx, w_hhT4, gru_b_hh, gi_table, tp_w, tp_b, z2p, z2f);
  // fused: wp2 (0..127) || znA (128..639)
  wp2zna_kernel<<<dim3(640), dim3(256), 0, stream>>>(
      x_enc, wp2, bp2, x_inst, x_lag, Z, z2f, ltn_w, ltn_b, zn_ws);
  // fused: adj (0..1023) || znB (1024..1535)
  adjznb_kernel<<<dim3(1536), dim3(256), 0, stream>>>(
      x_inst, x_lag, es_now, es_lag, prior, out,
      zn_ws, gat_wl, gat_bl, gat_wr, gat_br, xl, xr);
  // gat megakernel: e + softmax + xemb + gl-GEMM (outputs 2,3)
  gatmega_kernel<<<dim3(128), dim3(256), 0, stream>>>(
      xl, xr, gat_att, gat_bias, gl_w, gl_b,
      out + 2 * NN * NN, out + 3 * NN * NN);
}

// Round 21
// 160.632 us; speedup vs baseline: 1.5732x; 1.5732x over previous
//
#include <hip/hip_runtime.h>
#include <stdint.h>
#include <math.h>

// Sizes
#define NN 512   // N_NODES
#define HID 64
#define LAT 256
#define TS 10
#define BAT 64

#define DEVFN static __device__ __forceinline__

DEVFN uint32_t rotl32(uint32_t v, int d) { return (v << d) | (v >> (32 - d)); }

// Threefry-2x32, 20 rounds (JAX threefry2x32_p). key=(k0,k1), count=(x0,x1).
DEVFN void threefry2x32(uint32_t k0, uint32_t k1, uint32_t x0, uint32_t x1,
                        uint32_t& o0, uint32_t& o1) {
  uint32_t ks0 = k0, ks1 = k1, ks2 = k0 ^ k1 ^ 0x1BD11BDAu;
  x0 += ks0; x1 += ks1;
  x0 += x1; x1 = rotl32(x1, 13); x1 ^= x0;
  x0 += x1; x1 = rotl32(x1, 15); x1 ^= x0;
  x0 += x1; x1 = rotl32(x1, 26); x1 ^= x0;
  x0 += x1; x1 = rotl32(x1, 6);  x1 ^= x0;
  x0 += ks1; x1 += ks2 + 1u;
  x0 += x1; x1 = rotl32(x1, 17); x1 ^= x0;
  x0 += x1; x1 = rotl32(x1, 29); x1 ^= x0;
  x0 += x1; x1 = rotl32(x1, 16); x1 ^= x0;
  x0 += x1; x1 = rotl32(x1, 24); x1 ^= x0;
  x0 += ks2; x1 += ks0 + 2u;
  x0 += x1; x1 = rotl32(x1, 13); x1 ^= x0;
  x0 += x1; x1 = rotl32(x1, 15); x1 ^= x0;
  x0 += x1; x1 = rotl32(x1, 26); x1 ^= x0;
  x0 += x1; x1 = rotl32(x1, 6);  x1 ^= x0;
  x0 += ks0; x1 += ks1 + 3u;
  x0 += x1; x1 = rotl32(x1, 17); x1 ^= x0;
  x0 += x1; x1 = rotl32(x1, 29); x1 ^= x0;
  x0 += x1; x1 = rotl32(x1, 16); x1 ^= x0;
  x0 += x1; x1 = rotl32(x1, 24); x1 ^= x0;
  x0 += ks1; x1 += ks2 + 4u;
  x0 += x1; x1 = rotl32(x1, 13); x1 ^= x0;
  x0 += x1; x1 = rotl32(x1, 15); x1 ^= x0;
  x0 += x1; x1 = rotl32(x1, 26); x1 ^= x0;
  x0 += x1; x1 = rotl32(x1, 6);  x1 ^= x0;
  x0 += ks2; x1 += ks0 + 5u;
  o0 = x0; o1 = x1;
}

DEVFN float sigmoidf_(float x) { return 1.0f / (1.0f + expf(-x)); }

// JAX gumbel from 32 random bits: uniform in [tiny, 1), g = -log(-log(u))
DEVFN float gumbel_bits(uint32_t bits) {
  const float tiny = 1.17549435e-38f;
  float f = __uint_as_float((bits >> 9) | 0x3F800000u) - 1.0f;
  float u = f * (1.0f - tiny) + tiny;
  u = fmaxf(tiny, u);
  return -logf(-logf(u));
}

// 256-thread block reduction (4 waves of 64)
DEVFN float block_red256(float v, float* red, bool ismax) {
  #pragma unroll
  for (int o = 32; o > 0; o >>= 1) {
    float w = __shfl_down(v, o, 64);
    v = ismax ? fmaxf(v, w) : v + w;
  }
  if ((threadIdx.x & 63) == 0) red[threadIdx.x >> 6] = v;
  __syncthreads();
  float r = ismax ? fmaxf(fmaxf(red[0], red[1]), fmaxf(red[2], red[3]))
                  : ((red[0] + red[1]) + (red[2] + red[3]));
  __syncthreads();
  return r;
}

// 64-lane wave butterfly sum
DEVFN float wave_red_sum64(float v) {
  #pragma unroll
  for (int o = 32; o > 0; o >>= 1) v += __shfl_xor(v, o, 64);
  return v;
}

// float4 dot-step, k-ascending order preserved
#define ACC4(acc, x4, w4) { acc += (x4).x * (w4).x; acc += (x4).y * (w4).y; \
                            acc += (x4).z * (w4).z; acc += (x4).w * (w4).w; }

// ================ prep: whht || wp1 || gitab || flow (all independent) =========
__global__ __launch_bounds__(384) void prep_kernel(
    const float* __restrict__ w_hh, float* __restrict__ w_hhT,
    const float* __restrict__ X, const float* __restrict__ wp1,
    const float* __restrict__ bp1, float* __restrict__ x0,
    const float* __restrict__ w_ih, const float* __restrict__ b_ih,
    float* __restrict__ gi_table,
    const float* __restrict__ Z, const float* __restrict__ fs_w,
    const float* __restrict__ fs_b, const float* __restrict__ ft_w,
    const float* __restrict__ ft_b, float* __restrict__ z2p) {
  const int tid = threadIdx.x;
  if (blockIdx.x < 128) {
    // whht: k-chunk float4 transpose
    const int idx = blockIdx.x * 384 + tid;   // 128*384 = 49152
    const int k4 = idx / 1536, rem = idx % 1536;
    const int t = rem >> 2, kl = rem & 3;
    w_hhT[idx] = w_hh[(k4 * 4 + kl) * 384 + t];
  } else if (blockIdx.x < 288) {
    // wp1 (4 rows/block); compute guarded to tid<256
    const int r0 = (blockIdx.x - 128) * 4;
    const int g = tid >> 6, c = tid & 63;
    __shared__ float Xb[4][NN];      // 8KB
    __shared__ float Wb[128 * 64];   // 32KB, k-chunk float4 layout
    for (int i = tid; i < 4 * NN; i += 384)
      Xb[i >> 9][i & 511] = X[r0 * NN + i];
    float acc = (tid < 256) ? bp1[c] : 0.0f;
    for (int ch = 0; ch < 4; ch++) {
      const int n0 = ch * 128;
      __syncthreads();
      for (int i = tid; i < 128 * 64; i += 384) {
        int k = i >> 6, cc = i & 63;
        Wb[((k >> 2) * 64 + cc) * 4 + (k & 3)] = wp1[(n0 + k) * 64 + cc];
      }
      __syncthreads();
      if (tid < 256) {
        #pragma unroll 8
        for (int n4 = 0; n4 < 32; n4++) {
          float4 w4 = *(const float4*)&Wb[(n4 * 64 + c) * 4];
          float4 x4 = *(const float4*)&Xb[g][n0 + n4 * 4];
          ACC4(acc, x4, w4);
        }
      }
    }
    if (tid < 256) x0[(r0 + g) * HID + c] = acc;
  } else if (blockIdx.x < 388) {
    // gitab
    const int v = blockIdx.x - 288;  // 0..99
    const int t = tid;               // col 0..383
    __shared__ float temb[256];
    if (t < 256) {
      float fr = (float)exp((double)(t & 127) * (10.0 / 127.0));  // np f64->f32
      float arg = (float)v * fr;
      temb[t] = (t < 128) ? sinf(arg) : cosf(arg);
    }
    __syncthreads();
    float acc = b_ih[t];
    for (int k = 0; k < 256; k++) acc += temb[k] * w_ih[k * 384 + t];
    gi_table[v * 384 + t] = acc;
  } else {
    // flow: 3 nodes/block
    const int n = (blockIdx.x - 388) * 3 + (tid >> 7);
    const int c = tid & 127;
    __shared__ float z1s[3][128];
    if (n < NN) z1s[tid >> 7][c] = Z[n * LAT + c];
    __syncthreads();
    if (n < NN) {
      const float* z1 = z1s[tid >> 7];
      float a = fs_b[c], t = ft_b[c];
      for (int k = 0; k < 128; k++) {
        float zz = z1[k];
        a += zz * fs_w[k * 128 + c];
        t += zz * ft_w[k * 128 + c];
      }
      z2p[n * 128 + c] = sigmoidf_(a) * Z[n * LAT + 128 + c] + t;
    }
  }
}

// ================ fused enc (blocks 0..63) + gru 4-node (blocks 64..191) =======
__global__ __launch_bounds__(768) void encgru_kernel(
    const float* __restrict__ x0,
    const float* __restrict__ in_w, const float* __restrict__ in_b,
    const float* __restrict__ out_w, const float* __restrict__ out_b,
    const float* __restrict__ l1_w, const float* __restrict__ l1_b,
    const float* __restrict__ l2_w, const float* __restrict__ l2_b,
    const float* __restrict__ g1, const float* __restrict__ b1,
    const float* __restrict__ g2, const float* __restrict__ b2,
    float* __restrict__ x_enc,
    const int* __restrict__ tctx, const float* __restrict__ w_hhT4,
    const float* __restrict__ b_hh, const float* __restrict__ gi_table,
    const float* __restrict__ tp_w, const float* __restrict__ tp_b,
    const float* __restrict__ z2p, float* __restrict__ z2f) {
  __shared__ float smem[28176];   // 112.7KB union
  const int tid = threadIdx.x;

  if (blockIdx.x < 64) {
    const int b = blockIdx.x;
    const int s = tid >> 6, c = tid & 63;
    float* WbA  = smem;            // 12288
    float* WbB  = smem + 12288;    // 12288
    float* xx   = smem + 24576;    // 640
    float* qkv  = smem + 25216;    // 1920
    float* scb  = smem + 27136;    // 400
    float* tmpv = smem + 27536;    // 640

    if (tid < 640) xx[s * 64 + c] = x0[b * 640 + tid];

    for (int l = 0; l < 2; l++) {
      const float* inw = in_w + l * HID * 192; const float* inb = in_b + l * 192;
      const float* ow  = out_w + l * HID * HID; const float* ob = out_b + l * HID;
      const float* w1  = l1_w + l * HID * HID; const float* bb1 = l1_b + l * HID;
      const float* w2  = l2_w + l * HID * HID; const float* bb2 = l2_b + l * HID;
      const float* gg1 = g1 + l * HID; const float* be1 = b1 + l * HID;
      const float* gg2 = g2 + l * HID; const float* be2 = b2 + l * HID;

      __syncthreads();
      for (int i = tid; i < 12288; i += 768) {
        int k = i / 192, cc = i % 192;
        WbA[((k >> 2) * 192 + cc) * 4 + (k & 3)] = inw[i];
      }
      for (int i = tid; i < 12288; i += 768) {
        int m = i >> 12, rem = i & 4095, k = rem >> 6, cc = rem & 63;
        float v = (m == 0) ? ow[rem] : (m == 1) ? w1[rem] : w2[rem];
        WbB[m * 4096 + ((k >> 2) * 64 + cc) * 4 + (k & 3)] = v;
      }
      __syncthreads();

      if (tid < 640) {
        #pragma unroll
        for (int part = 0; part < 3; part++) {
          const int cc = part * 64 + c;
          float acc = inb[cc];
          #pragma unroll
          for (int k4 = 0; k4 < 16; k4++) {
            float4 w4 = *(const float4*)&WbA[(k4 * 192 + cc) * 4];
            float4 x4 = *(const float4*)&xx[s * 64 + k4 * 4];
            ACC4(acc, x4, w4);
          }
          qkv[s * 192 + cc] = acc;
        }
      }
      __syncthreads();

      if (tid < 40) {
        const int h = tid / 10, r = tid % 10;
        float e[10];
        for (int t = 0; t < 10; t++) {
          float acc = 0.0f;
          for (int d = 0; d < 16; d++)
            acc += qkv[r * 192 + h * 16 + d] * qkv[t * 192 + 64 + h * 16 + d];
          e[t] = acc * 0.25f;
        }
        float m = -1e30f;
        for (int t = 0; t < 10; t++) m = fmaxf(m, e[t]);
        float sum = 0.0f;
        for (int t = 0; t < 10; t++) { e[t] = expf(e[t] - m); sum += e[t]; }
        float inv = 1.0f / sum;
        for (int t = 0; t < 10; t++) scb[h * 100 + r * 10 + t] = e[t] * inv;
      }
      __syncthreads();

      float v1 = 0.0f;
      if (tid < 640) {
        const int h = c >> 4;
        float acc = 0.0f;
        for (int t = 0; t < 10; t++)
          acc += scb[h * 100 + s * 10 + t] * qkv[t * 192 + 128 + c];
        tmpv[s * 64 + c] = acc;
      }
      __threadfence_block();
      if (tid < 640) {
        float acc = ob[c] + xx[s * 64 + c];
        #pragma unroll
        for (int k4 = 0; k4 < 16; k4++) {
          float4 w4 = *(const float4*)&WbB[(k4 * 64 + c) * 4];
          float4 x4 = *(const float4*)&tmpv[s * 64 + k4 * 4];
          ACC4(acc, x4, w4);
        }
        float mu = wave_red_sum64(acc) * (1.0f / 64.0f);
        float d = acc - mu;
        float var = wave_red_sum64(d * d) * (1.0f / 64.0f);
        float rs = rsqrtf(var + 1e-5f);
        v1 = d * rs * gg1[c] + be1[c];
        xx[s * 64 + c] = v1;
      }
      __threadfence_block();
      if (tid < 640) {
        float acc = bb1[c];
        #pragma unroll
        for (int k4 = 0; k4 < 16; k4++) {
          float4 w4 = *(const float4*)&WbB[4096 + (k4 * 64 + c) * 4];
          float4 x4 = *(const float4*)&xx[s * 64 + k4 * 4];
          ACC4(acc, x4, w4);
        }
        tmpv[s * 64 + c] = fmaxf(acc, 0.0f);
      }
      __threadfence_block();
      if (tid < 640) {
        float acc = bb2[c] + v1;
        #pragma unroll
        for (int k4 = 0; k4 < 16; k4++) {
          float4 w4 = *(const float4*)&WbB[8192 + (k4 * 64 + c) * 4];
          float4 x4 = *(const float4*)&tmpv[s * 64 + k4 * 4];
          ACC4(acc, x4, w4);
        }
        float mu = wave_red_sum64(acc) * (1.0f / 64.0f);
        float d = acc - mu;
        float var = wave_red_sum64(d * d) * (1.0f / 64.0f);
        float rs = rsqrtf(var + 1e-5f);
        xx[s * 64 + c] = d * rs * gg2[c] + be2[c];
      }
      __threadfence_block();
    }
    if (tid < 640) x_enc[b * 640 + tid] = xx[s * 64 + c];
  } else {
    const int n0 = (blockIdx.x - 64) * 4;
    const int half = tid >= 384 ? 1 : 0;
    const int c = tid - half * 384;
    float* h      = smem;             // 512
    float* part   = smem + 512;       // 3072
    float* gi_lds = smem + 3584;      // 15360
    float* tpw    = smem + 18944;     // 10
    for (int i = tid; i < 4 * TS * 384; i += 768) {
      int g = i / 3840, rem = i % 3840, s = rem / 384, col = rem % 384;
      gi_lds[(g * TS + s) * 384 + col] = gi_table[tctx[(n0 + g) * 10 + s] * 384 + col];
    }
    if (tid < TS) tpw[tid] = tp_w[tid];
    const float4* wbase = (const float4*)w_hhT4 + (half * 16) * 384 + c;
    const float bhh = (half == 0) ? b_hh[c] : 0.0f;
    float acc_tp = 0.0f;
    if (tid < 512) h[tid] = 0.0f;
    __syncthreads();
    #pragma unroll
    for (int s = 0; s < 10; s++) {
      float accs[4];
      #pragma unroll
      for (int g = 0; g < 4; g++) accs[g] = bhh;
      #pragma unroll
      for (int k4 = 0; k4 < 16; k4++) {
        float4 w4 = wbase[k4 * 384];
        #pragma unroll
        for (int g = 0; g < 4; g++) {
          float4 hv = *(const float4*)&h[g * 128 + (half * 16 + k4) * 4];
          ACC4(accs[g], hv, w4);
        }
      }
      #pragma unroll
      for (int g = 0; g < 4; g++) part[(half * 4 + g) * 384 + c] = accs[g];
      __syncthreads();
      if (tid < 512) {
        const int g = tid >> 7, cc = tid & 127;
        const float* gi = gi_lds + (g * TS + s) * 384;
        float gh_r = part[g * 384 + cc]           + part[(4 + g) * 384 + cc];
        float gh_z = part[g * 384 + 128 + cc]     + part[(4 + g) * 384 + 128 + cc];
        float gh_n = part[g * 384 + 256 + cc]     + part[(4 + g) * 384 + 256 + cc];
        float r = sigmoidf_(gi[cc] + gh_r);
        float z = sigmoidf_(gi[128 + cc] + gh_z);
        float nn2 = tanhf(gi[256 + cc] + r * gh_n);
        float hn = (1.0f - z) * nn2 + z * h[g * 128 + cc];
        h[g * 128 + cc] = hn;
        acc_tp += hn * tpw[s];
      }
      __syncthreads();
    }
    if (tid < 512) {
      const int g = tid >> 7, cc = tid & 127;
      z2f[(n0 + g) * 128 + cc] = z2p[(n0 + g) * 128 + cc] + acc_tp + tp_b[0];
    }
  }
}

// ================ fused wp2 (blocks 0..127) + znA (blocks 128..639) ============
__global__ __launch_bounds__(256) void wp2zna_kernel(
    const float* __restrict__ x_enc, const float* __restrict__ wp2,
    const float* __restrict__ bp2,
    float* __restrict__ x_inst, float* __restrict__ x_lag,
    const float* __restrict__ Z, const float* __restrict__ z2f,
    const float* __restrict__ ltn_w, const float* __restrict__ ltn_b,
    float* __restrict__ zn_ws) {
  const int tid = threadIdx.x;
  if (blockIdx.x < 128) {
    const int b = blockIdx.x >> 1, half = blockIdx.x & 1;
    const int n = half * 256 + tid;
    __shared__ float xxl[640];
    __shared__ float Wb[32 * 256];   // 32KB
    for (int i = tid; i < 640; i += 256) xxl[i] = x_enc[b * 640 + i];
    float accs[10];
    #pragma unroll
    for (int si = 0; si < 10; si++) accs[si] = 0.0f;
    for (int ch = 0; ch < 2; ch++) {
      __syncthreads();
      for (int i = tid; i < 32 * 256; i += 256)
        Wb[i] = wp2[(ch * 32 + (i >> 8)) * NN + half * 256 + (i & 255)];
      __syncthreads();
      for (int k = 0; k < 32; k++) {
        float w = Wb[k * 256 + tid];
        #pragma unroll
        for (int si = 0; si < 10; si++) accs[si] += xxl[si * 64 + ch * 32 + k] * w;
      }
    }
    float bias = bp2[n];
    x_inst[b * NN + n] = accs[0] + bias;
    float lag = 0.0f;
    for (int si = 1; si < 10; si++) lag += accs[si];
    x_lag[b * NN + n] = lag * (1.0f / 9.0f) + bias;
  } else {
    const int bid = blockIdx.x - 128;
    const int nt = bid >> 2, cg = bid & 3;
    const int oo = tid & 127, gsel = tid >> 7;
    const int o = cg * 128 + oo;
    const int n0 = nt * 4;
    __shared__ float zcat[4][LAT];   // 4KB
    for (int i = tid; i < 4 * LAT; i += 256) {
      int g = i >> 8, k = i & 255;
      zcat[g][k] = (k < 128) ? Z[(n0 + g) * LAT + k] : z2f[(n0 + g) * 128 + (k - 128)];
    }
    __syncthreads();
    const float bias = ltn_b[o];
    float accA = bias, accB = bias;
    const int g0 = gsel, g1 = gsel + 2;
    for (int k = 0; k < LAT; k++) {
      float w = ltn_w[k * NN + o];
      accA += zcat[g0][k] * w;
      accB += zcat[g1][k] * w;
    }
    zn_ws[(n0 + g0) * NN + o] = accA;
    zn_ws[(n0 + g1) * NN + o] = accB;
  }
}

// ================ fused adj (blocks 0..1023) + znB (blocks 1024..1535) =========
__global__ __launch_bounds__(256) void adjznb_kernel(
    const float* __restrict__ x_inst, const float* __restrict__ x_lag,
    const float* __restrict__ es_now, const float* __restrict__ es_lag,
    const float* __restrict__ prior, float* __restrict__ out,
    const float* __restrict__ zn_ws,
    const float* __restrict__ wl, const float* __restrict__ bl,
    const float* __restrict__ wr, const float* __restrict__ br,
    float* __restrict__ xl, float* __restrict__ xr) {
  const int tid = threadIdx.x;
  if (blockIdx.x < 1024) {
    const int k = blockIdx.x & 511;
    const int v = blockIdx.x >> 9;
    const float* xs = v ? x_lag : x_inst;
    const float* es = v ? es_lag : es_now;
    __shared__ float ck[BAT];
    __shared__ float red[4];
    if (tid < BAT) ck[tid] = xs[tid * NN + k];
    __syncthreads();
    uint32_t ka, kb, t0, t1;
    threefry2x32(0u, 42u, 0u, (uint32_t)v, ka, kb);
    float vals[2];
    #pragma unroll
    for (int jj = 0; jj < 2; jj++) {
      int j = tid + jj * 256;
      float acc = 0.0f;
      for (int bb = 0; bb < BAT; bb++) acc += ck[bb] * xs[bb * NN + j];
      if (v) acc = sigmoidf_(acc);
      threefry2x32(ka, kb, 0u, (uint32_t)(k * NN + j), t0, t1);
      vals[jj] = acc + gumbel_bits(t0 ^ t1);
    }
    float m = block_red256(fmaxf(vals[0], vals[1]), red, true);
    float e0 = expf(vals[0] - m), e1 = expf(vals[1] - m);
    float s = block_red256(e0 + e1, red, false);
    float inv = 1.0f / s;
    #pragma unroll
    for (int jj = 0; jj < 2; jj++) {
      int j = tid + jj * 256;
      float a = (jj ? e1 : e0) * inv;
      float t = es[k * NN + j] + prior[k * NN + j] + a;
      float sg = sigmoidf_(t);
      sg = fminf(fmaxf(sg, 0.0f), 1.0f);
      if (j == k) sg = 0.0f;
      if (sg == 0.0f) sg = 1e-8f;
      out[v * NN * NN + k * NN + j] = sg;
    }
  } else {
    const int bid = blockIdx.x - 1024;
    const int nt = bid >> 2, cg = bid & 3;
    const int o = cg * 64 + (tid & 63), g = tid >> 6;
    const int n = nt * 4 + g;
    __shared__ float znr[4][NN];   // 8KB
    for (int i = tid; i < 4 * NN; i += 256)
      znr[i >> 9][i & 511] = zn_ws[(nt * 4 + (i >> 9)) * NN + (i & 511)];
    __syncthreads();
    float accL = bl[o], accR = br[o];
    for (int k = 0; k < NN; k++) {
      float z = znr[g][k];
      accL += z * wl[k * 256 + o];
      accR += z * wr[k * 256 + o];
    }
    xl[n * 256 + o] = accL;
    xr[n * 256 + o] = accR;
  }
}

// ---------------- gatE4: e tile 16i x 64j x 1h; grid 1024 ----------------------
__global__ __launch_bounds__(256) void gatE4_kernel(
    const float* __restrict__ xl, const float* __restrict__ xr,
    const float* __restrict__ attw, float* __restrict__ e_ws) {
  const int b = blockIdx.x;
  const int jt = b & 7, h = (b >> 3) & 3, it = b >> 5;
  const int tid = threadIdx.x;
  const int i_l = tid >> 4, jq = tid & 15;
  __shared__ float xlt[64][68];   // 17KB  [c][j] padded
  __shared__ float xrt[16][68];   // 4.25KB [i][c] padded
  __shared__ float awl[64];
  for (int idx = tid; idx < 1024; idx += 256) {
    int j = idx >> 4, c4 = idx & 15;
    float4 v = *(const float4*)&xl[(jt * 64 + j) * 256 + h * 64 + c4 * 4];
    xlt[c4 * 4 + 0][j] = v.x;
    xlt[c4 * 4 + 1][j] = v.y;
    xlt[c4 * 4 + 2][j] = v.z;
    xlt[c4 * 4 + 3][j] = v.w;
  }
  for (int idx = tid; idx < 1024; idx += 256) {
    int i = idx >> 6, cc = idx & 63;
    xrt[i][cc] = xr[(it * 16 + i) * 256 + h * 64 + cc];
  }
  if (tid < 64) awl[tid] = attw[h * 64 + tid];
  __syncthreads();
  float acc0 = 0.0f, acc1 = 0.0f, acc2 = 0.0f, acc3 = 0.0f;
  #pragma unroll
  for (int c4 = 0; c4 < 16; c4++) {
    float4 aw4 = *(const float4*)&awl[c4 * 4];
    float4 xr4 = *(const float4*)&xrt[i_l][c4 * 4];
    float4 xl0 = *(const float4*)&xlt[c4 * 4 + 0][jq * 4];
    float4 xl1 = *(const float4*)&xlt[c4 * 4 + 1][jq * 4];
    float4 xl2 = *(const float4*)&xlt[c4 * 4 + 2][jq * 4];
    float4 xl3 = *(const float4*)&xlt[c4 * 4 + 3][jq * 4];
    {
      float v0 = xr4.x + xl0.x; v0 = (v0 >= 0.0f) ? v0 : 0.2f * v0;
      float v1 = xr4.x + xl0.y; v1 = (v1 >= 0.0f) ? v1 : 0.2f * v1;
      float v2 = xr4.x + xl0.z; v2 = (v2 >= 0.0f) ? v2 : 0.2f * v2;
      float v3 = xr4.x + xl0.w; v3 = (v3 >= 0.0f) ? v3 : 0.2f * v3;
      acc0 += v0 * aw4.x; acc1 += v1 * aw4.x; acc2 += v2 * aw4.x; acc3 += v3 * aw4.x;
    }
    {
      float v0 = xr4.y + xl1.x; v0 = (v0 >= 0.0f) ? v0 : 0.2f * v0;
      float v1 = xr4.y + xl1.y; v1 = (v1 >= 0.0f) ? v1 : 0.2f * v1;
      float v2 = xr4.y + xl1.z; v2 = (v2 >= 0.0f) ? v2 : 0.2f * v2;
      float v3 = xr4.y + xl1.w; v3 = (v3 >= 0.0f) ? v3 : 0.2f * v3;
      acc0 += v0 * aw4.y; acc1 += v1 * aw4.y; acc2 += v2 * aw4.y; acc3 += v3 * aw4.y;
    }
    {
      float v0 = xr4.z + xl2.x; v0 = (v0 >= 0.0f) ? v0 : 0.2f * v0;
      float v1 = xr4.z + xl2.y; v1 = (v1 >= 0.0f) ? v1 : 0.2f * v1;
      float v2 = xr4.z + xl2.z; v2 = (v2 >= 0.0f) ? v2 : 0.2f * v2;
      float v3 = xr4.z + xl2.w; v3 = (v3 >= 0.0f) ? v3 : 0.2f * v3;
      acc0 += v0 * aw4.z; acc1 += v1 * aw4.z; acc2 += v2 * aw4.z; acc3 += v3 * aw4.z;
    }
    {
      float v0 = xr4.w + xl3.x; v0 = (v0 >= 0.0f) ? v0 : 0.2f * v0;
      float v1 = xr4.w + xl3.y; v1 = (v1 >= 0.0f) ? v1 : 0.2f * v1;
      float v2 = xr4.w + xl3.z; v2 = (v2 >= 0.0f) ? v2 : 0.2f * v2;
      float v3 = xr4.w + xl3.w; v3 = (v3 >= 0.0f) ? v3 : 0.2f * v3;
      acc0 += v0 * aw4.w; acc1 += v1 * aw4.w; acc2 += v2 * aw4.w; acc3 += v3 * aw4.w;
    }
  }
  const int i = it * 16 + i_l;
  float* dst = e_ws + i * 2048 + h * 512 + jt * 64 + jq * 4;
  dst[0] = acc0; dst[1] = acc1; dst[2] = acc2; dst[3] = acc3;
}

// -------- gatSX: softmax (gatS reduction order) + matvec, fused ----------------
__global__ __launch_bounds__(256) void gatSX_kernel(
    const float* __restrict__ e_ws, const float* __restrict__ xl,
    const float* __restrict__ gbias, float* __restrict__ xemb) {
  const int it = blockIdx.x >> 2, h = blockIdx.x & 3;
  const int tid = threadIdx.x;
  const int cq = tid & 15, jp = (tid >> 4) & 3, ip = tid >> 6;
  __shared__ float al[4][512];   // 8KB raw e rows for this head
  __shared__ float red[4];
  for (int i = tid; i < 4 * 512; i += 256)
    al[i >> 9][i & 511] = e_ws[(it * 4 + (i >> 9)) * 2048 + h * 512 + (i & 511)];
  __syncthreads();
  #pragma unroll
  for (int ii = 0; ii < 4; ii++) {
    float v0 = al[ii][tid], v1 = al[ii][256 + tid];
    float m = block_red256(fmaxf(v0, v1), red, true);
    float e0 = expf(v0 - m), e1 = expf(v1 - m);
    float ssum = block_red256(e0 + e1, red, false);
    float inv = 1.0f / ssum;
    al[ii][tid] = e0 * inv;
    al[ii][256 + tid] = e1 * inv;
  }
  __syncthreads();
  float acc0 = 0.0f, acc1 = 0.0f, acc2 = 0.0f, acc3 = 0.0f;
  #pragma unroll 4
  for (int js = 0; js < 128; js++) {
    const int j = js * 4 + jp;
    float4 x4 = *(const float4*)&xl[j * 256 + h * 64 + cq * 4];
    float a = al[ip][j];
    acc0 += a * x4.x; acc1 += a * x4.y; acc2 += a * x4.z; acc3 += a * x4.w;
  }
  acc0 += __shfl_xor(acc0, 16, 64); acc0 += __shfl_xor(acc0, 32, 64);
  acc1 += __shfl_xor(acc1, 16, 64); acc1 += __shfl_xor(acc1, 32, 64);
  acc2 += __shfl_xor(acc2, 16, 64); acc2 += __shfl_xor(acc2, 32, 64);
  acc3 += __shfl_xor(acc3, 16, 64); acc3 += __shfl_xor(acc3, 32, 64);
  if (jp == 0) {
    const int i = it * 4 + ip;
    const int o = h * 64 + cq * 4;
    float4 v = make_float4(acc0 + gbias[o],     acc1 + gbias[o + 1],
                           acc2 + gbias[o + 2], acc3 + gbias[o + 3]);
    *(float4*)&xemb[i * 256 + o] = v;
  }
}

// ---------------- fallback fused GAT (2 targets/block) if ws too small ---------
__global__ __launch_bounds__(256) void gat_fused_kernel(
    const float* __restrict__ xl, const float* __restrict__ xr,
    const float* __restrict__ attw, const float* __restrict__ gbias,
    float* __restrict__ xemb) {
  const int i0 = blockIdx.x * 2, tid = threadIdx.x;
  __shared__ float xri[2][256];
  __shared__ float aw[256];
  __shared__ float e[2][4][NN];
  __shared__ float part[4][2][256];
  __shared__ float red[4];
  xri[0][tid] = xr[i0 * 256 + tid];
  xri[1][tid] = xr[(i0 + 1) * 256 + tid];
  aw[tid] = attw[tid];
  __syncthreads();
  #pragma unroll
  for (int jj = 0; jj < 2; jj++) {
    const int j = tid + jj * 256;
    const float4* xl4 = (const float4*)(xl + j * 256);
    #pragma unroll
    for (int hh = 0; hh < 4; hh++) {
      float accA = 0.0f, accB = 0.0f;
      #pragma unroll 4
      for (int c4 = 0; c4 < 16; c4++) {
        float4 v = xl4[hh * 16 + c4];
        const int cb = hh * 64 + c4 * 4;
        float w0 = aw[cb + 0], w1 = aw[cb + 1], w2 = aw[cb + 2], w3 = aw[cb + 3];
        float a0 = xri[0][cb + 0] + v.x; a0 = (a0 >= 0.0f) ? a0 : 0.2f * a0;
        float a1 = xri[0][cb + 1] + v.y; a1 = (a1 >= 0.0f) ? a1 : 0.2f * a1;
        float a2 = xri[0][cb + 2] + v.z; a2 = (a2 >= 0.0f) ? a2 : 0.2f * a2;
        float a3 = xri[0][cb + 3] + v.w; a3 = (a3 >= 0.0f) ? a3 : 0.2f * a3;
        accA += a0 * w0; accA += a1 * w1; accA += a2 * w2; accA += a3 * w3;
        float b0 = xri[1][cb + 0] + v.x; b0 = (b0 >= 0.0f) ? b0 : 0.2f * b0;
        float b1 = xri[1][cb + 1] + v.y; b1 = (b1 >= 0.0f) ? b1 : 0.2f * b1;
        float b2 = xri[1][cb + 2] + v.z; b2 = (b2 >= 0.0f) ? b2 : 0.2f * b2;
        float b3 = xri[1][cb + 3] + v.w; b3 = (b3 >= 0.0f) ? b3 : 0.2f * b3;
        accB += b0 * w0; accB += b1 * w1; accB += b2 * w2; accB += b3 * w3;
      }
      e[0][hh][j] = accA;
      e[1][hh][j] = accB;
    }
  }
  __syncthreads();
  for (int ii = 0; ii < 2; ii++) {
    for (int hh = 0; hh < 4; hh++) {
      float v0 = e[ii][hh][tid], v1 = e[ii][hh][tid + 256];
      float m = block_red256(fmaxf(v0, v1), red, true);
      float e0 = expf(v0 - m), e1 = expf(v1 - m);
      float ssum = block_red256(e0 + e1, red, false);
      float inv = 1.0f / ssum;
      e[ii][hh][tid] = e0 * inv;
      e[ii][hh][tid + 256] = e1 * inv;
    }
  }
  __syncthreads();
  {
    const int w = tid >> 6, lane = tid & 63;
    float a0 = 0.0f, a1 = 0.0f, a2 = 0.0f, a3 = 0.0f;
    float b0 = 0.0f, b1 = 0.0f, b2 = 0.0f, b3 = 0.0f;
    const int j0 = w * 128;
    for (int j = j0; j < j0 + 128; j++) {
      const float* xlr = xl + j * 256 + lane;
      float x0 = xlr[0], x1 = xlr[64], x2 = xlr[128], x3 = xlr[192];
      a0 += e[0][0][j] * x0; a1 += e[0][1][j] * x1;
      a2 += e[0][2][j] * x2; a3 += e[0][3][j] * x3;
      b0 += e[1][0][j] * x0; b1 += e[1][1][j] * x1;
      b2 += e[1][2][j] * x2; b3 += e[1][3][j] * x3;
    }
    part[w][0][lane]       = a0;
    part[w][0][64 + lane]  = a1;
    part[w][0][128 + lane] = a2;
    part[w][0][192 + lane] = a3;
    part[w][1][lane]       = b0;
    part[w][1][64 + lane]  = b1;
    part[w][1][128 + lane] = b2;
    part[w][1][192 + lane] = b3;
  }
  __syncthreads();
  {
    float accA = ((part[0][0][tid] + part[1][0][tid]) + part[2][0][tid]) + part[3][0][tid];
    float accB = ((part[0][1][tid] + part[1][1][tid]) + part[2][1][tid]) + part[3][1][tid];
    float gb = gbias[tid];
    xemb[i0 * 256 + tid] = accA + gb;
    xemb[(i0 + 1) * 256 + tid] = accB + gb;
  }
}

// ---------------- ml = x_emb @ gl_w + gl_b (tiled); mean/scale epilogue --------
__global__ __launch_bounds__(256) void glgemm_kernel(
    const float* __restrict__ xemb, const float* __restrict__ gl_w,
    const float* __restrict__ gl_b, float* __restrict__ out_mean,
    float* __restrict__ out_scale) {
  const int ct = blockIdx.x & 15, it = blockIdx.x >> 4;
  const int tid = threadIdx.x;
  const int i0 = it * 16, col = ct * 64 + (tid & 63), ti = tid >> 6;
  __shared__ float xe[16][LAT];   // 16KB
  for (int o = tid; o < 16 * LAT; o += 256) {
    xe[o >> 8][o & 255] = xemb[(i0 + (o >> 8)) * LAT + (o & 255)];
  }
  __syncthreads();
  const float bias = gl_b[col];
  float acc0 = bias, acc1 = bias, acc2 = bias, acc3 = bias;
  const int r0 = ti * 4;
  #pragma unroll 4
  for (int k = 0; k < LAT; k++) {
    float w = gl_w[k * 1024 + col];
    acc0 += xe[r0 + 0][k] * w;
    acc1 += xe[r0 + 1][k] * w;
    acc2 += xe[r0 + 2][k] * w;
    acc3 += xe[r0 + 3][k] * w;
  }
  float accs[4] = {acc0, acc1, acc2, acc3};
  if (col < 512) {
    #pragma unroll
    for (int q = 0; q < 4; q++) out_mean[(i0 + r0 + q) * NN + col] = accs[q];
  } else {
    #pragma unroll
    for (int q = 0; q < 4; q++) {
      float lv = fminf(fmaxf(accs[q], -5.0f), 2.0f);
      out_scale[(i0 + r0 + q) * NN + (col - 512)] = expf(0.5f * lv);
    }
  }
}

extern "C" void kernel_launch(void* const* d_in, const int* in_sizes, int n_in,
                              void* d_out, int out_size, void* d_ws, size_t ws_size,
                              hipStream_t stream) {
  (void)in_sizes; (void)n_in; (void)out_size;
  const float* X        = (const float*)d_in[0];
  const float* Z        = (const float*)d_in[1];
  const float* es_now   = (const float*)d_in[2];
  const float* es_lag   = (const float*)d_in[3];
  const float* prior    = (const float*)d_in[4];
  const float* wp1      = (const float*)d_in[5];
  const float* bp1      = (const float*)d_in[6];
  const float* enc_in_w = (const float*)d_in[7];
  const float* enc_in_b = (const float*)d_in[8];
  const float* enc_out_w= (const float*)d_in[9];
  const float* enc_out_b= (const float*)d_in[10];
  const float* enc_l1_w = (const float*)d_in[11];
  const float* enc_l1_b = (const float*)d_in[12];
  const float* enc_l2_w = (const float*)d_in[13];
  const float* enc_l2_b = (const float*)d_in[14];
  const float* enc_g1   = (const float*)d_in[15];
  const float* enc_b1   = (const float*)d_in[16];
  const float* enc_g2   = (const float*)d_in[17];
  const float* enc_b2   = (const float*)d_in[18];
  const float* wp2      = (const float*)d_in[19];
  const float* bp2      = (const float*)d_in[20];
  const float* fs_w     = (const float*)d_in[21];
  const float* fs_b     = (const float*)d_in[22];
  const float* ft_w     = (const float*)d_in[23];
  const float* ft_b     = (const float*)d_in[24];
  const float* gru_w_ih = (const float*)d_in[25];
  const float* gru_w_hh = (const float*)d_in[26];
  const float* gru_b_ih = (const float*)d_in[27];
  const float* gru_b_hh = (const float*)d_in[28];
  const float* tp_w     = (const float*)d_in[29];
  const float* tp_b     = (const float*)d_in[30];
  const float* ltn_w    = (const float*)d_in[31];
  const float* ltn_b    = (const float*)d_in[32];
  const float* gat_wl   = (const float*)d_in[33];
  const float* gat_bl   = (const float*)d_in[34];
  const float* gat_wr   = (const float*)d_in[35];
  const float* gat_br   = (const float*)d_in[36];
  const float* gat_att  = (const float*)d_in[37];
  const float* gat_bias = (const float*)d_in[38];
  const float* gl_w     = (const float*)d_in[39];
  const float* gl_b     = (const float*)d_in[40];
  const int*   tctx     = (const int*)d_in[41];

  float* out = (float*)d_out;
  float* ws  = (float*)d_ws;
  // ws layout (floats)
  float* x_inst   = ws;                // 64*512
  float* x_lag    = ws + 32768;        // 64*512
  float* z2p      = ws + 65536;        // 512*128
  float* z2f      = ws + 131072;       // 512*128
  float* xl       = ws + 196608;       // 512*256
  float* xr       = ws + 327680;       // 512*256
  float* gi_table = ws + 458752;       // 100*384
  float* xemb     = ws + 497152;       // 512*256
  float* x0       = ws + 628224;       // 640*64
  float* x_enc    = ws + 669184;       // 640*64
  float* zn_ws    = ws + 710144;       // 512*512
  float* e_ws     = ws + 972288;       // 512*2048 (4MB) — only if ws big enough
  float* w_hhT4   = zn_ws;             // aliased; gru done before znA writes

  const bool big_ws = ws_size >= (size_t)(972288 + 512 * 2048) * 4;

  // fused pre-phase: whht || wp1 || gitab || flow (all independent)
  prep_kernel<<<dim3(559), dim3(384), 0, stream>>>(
      gru_w_hh, w_hhT4, X, wp1, bp1, x0,
      gru_w_ih, gru_b_ih, gi_table,
      Z, fs_w, fs_b, ft_w, ft_b, z2p);
  // fused: enc (blocks 0..63) || gru (blocks 64..191)
  encgru_kernel<<<dim3(192), dim3(768), 0, stream>>>(
      x0, enc_in_w, enc_in_b, enc_out_w, enc_out_b,
      enc_l1_w, enc_l1_b, enc_l2_w, enc_l2_b,
      enc_g1, enc_b1, enc_g2, enc_b2, x_enc,
      tctx, w_hhT4, gru_b_hh, gi_table, tp_w, tp_b, z2p, z2f);
  // fused: wp2 (0..127) || znA (128..639)
  wp2zna_kernel<<<dim3(640), dim3(256), 0, stream>>>(
      x_enc, wp2, bp2, x_inst, x_lag, Z, z2f, ltn_w, ltn_b, zn_ws);
  // fused: adj (0..1023) || znB (1024..1535)
  adjznb_kernel<<<dim3(1536), dim3(256), 0, stream>>>(
      x_inst, x_lag, es_now, es_lag, prior, out,
      zn_ws, gat_wl, gat_bl, gat_wr, gat_br, xl, xr);
  if (big_ws) {
    gatE4_kernel<<<dim3(1024), dim3(256), 0, stream>>>(xl, xr, gat_att, e_ws);
    gatSX_kernel<<<dim3(512), dim3(256), 0, stream>>>(e_ws, xl, gat_bias, xemb);
  } else {
    gat_fused_kernel<<<dim3(NN / 2), dim3(256), 0, stream>>>(
        xl, xr, gat_att, gat_bias, xemb);
  }
  glgemm_kernel<<<dim3(512), dim3(256), 0, stream>>>(
      xemb, gl_w, gl_b, out + 2 * NN * NN, out + 3 * NN * NN);
}